// Round 5
// baseline (585.096 us; speedup 1.0000x reference)
//
#include <hip/hip_runtime.h>
#include <math.h>

#define H 128
#define BN_EPS 1e-5f

typedef __attribute__((ext_vector_type(8))) short bf16x8;
typedef __attribute__((ext_vector_type(4))) float f32x4;

__device__ __forceinline__ unsigned short f2bf(float f) {
    unsigned int u = __float_as_uint(f);
    u += 0x7fffu + ((u >> 16) & 1u);
    return (unsigned short)(u >> 16);
}
__device__ __forceinline__ float bf2f(unsigned short s) {
    return __uint_as_float(((unsigned int)s) << 16);
}
__device__ __forceinline__ f32x4 mfma16(bf16x8 a, bf16x8 b, f32x4 c) {
    return __builtin_amdgcn_mfma_f32_16x16x32_bf16(a, b, c, 0, 0, 0);
}

// ---------------------------------------------------------------------------
// Weight fragment pre-transpose into MFMA B-operand layout (bf16):
// dst[((kc*ntn+nt)*64+l)*8+j] = src[kc*32+(l>>4)*8+j][nt*16+(l&15)]
// ---------------------------------------------------------------------------
__device__ __forceinline__ void wfrag_one(const float* __restrict__ src,
                                          unsigned short* __restrict__ dst,
                                          int K, int N, int idx) {
    int l = idx & 63;
    int rest = idx >> 6;
    int ntn = N >> 4;
    int nt = rest % ntn;
    int kc = rest / ntn;
    int n = nt * 16 + (l & 15);
    int k0 = kc * 32 + (l >> 4) * 8;
    bf16x8 v;
    #pragma unroll
    for (int j = 0; j < 8; ++j) {
        int k = k0 + j;
        v[j] = (short)((k < K) ? f2bf(src[(size_t)k * N + n]) : 0);
    }
    *(bf16x8*)(dst + (size_t)idx * 8) = v;
}

__global__ __launch_bounds__(256)
void wfrag_all(const float* __restrict__ W1, const float* __restrict__ W2,
               const float* __restrict__ pu, const float* __restrict__ pr,
               const float* __restrict__ Wl, const float* __restrict__ Wr,
               unsigned short* __restrict__ W1f, unsigned short* __restrict__ W2f,
               unsigned short* __restrict__ puf, unsigned short* __restrict__ prf,
               unsigned short* __restrict__ sageWf) {
    int bx = blockIdx.x;
    if (bx < 26) {
        int idx = bx * 256 + threadIdx.x;
        if (idx < 4608)      wfrag_one(W1, W1f, 272, 128, idx);          // K=272 pad 288
        else if (idx < 5632) wfrag_one(W2, W2f, 128, 64, idx - 4608);
        else if (idx < 6144) wfrag_one(pu, puf, 32, 128, idx - 5632);
        else if (idx < 6656) wfrag_one(pr, prf, 32, 128, idx - 6144);
    } else {
        int idx = (bx - 26) * 256 + threadIdx.x;   // < 16384
        int seg = idx >> 11;                        // 0..7
        int sub = idx & 2047;
        int lt = seg >> 1;                          // layer*2+type
        int half = seg & 1;                         // 0=Wl, 1=Wr
        const float* src = (half ? Wr : Wl) + (size_t)lt * H * H;
        unsigned short* dst = sageWf + (size_t)lt * 32768 + half * 16384;
        wfrag_one(src, dst, 128, 128, sub);
    }
}

// ---------------------------------------------------------------------------
// Input projection via MFMA: hb = bf16(x @ W + b)
// ---------------------------------------------------------------------------
__global__ __launch_bounds__(256)
void proj_kernel(const float* __restrict__ xu, const float* __restrict__ xr,
                 const unsigned short* __restrict__ puf, const float* __restrict__ bu,
                 const unsigned short* __restrict__ prf, const float* __restrict__ br,
                 unsigned short* __restrict__ hub, unsigned short* __restrict__ hrb,
                 int Nu, int Nr, int nbu) {
    int bx = blockIdx.x;
    const float* x; const unsigned short* Wf; const float* bias;
    unsigned short* hb; int N; int row0;
    if (bx < nbu) { x = xu; Wf = puf; bias = bu; hb = hub; N = Nu; row0 = bx * 64; }
    else          { x = xr; Wf = prf; bias = br; hb = hrb; N = Nr; row0 = (bx - nbu) * 64; }

    int tid = threadIdx.x, l = tid & 63, w = tid >> 6, l15 = l & 15, quad = l >> 4;
    int arow = row0 + w * 16 + l15;

    bf16x8 a = {0, 0, 0, 0, 0, 0, 0, 0};
    if (arow < N) {
        const float* xp = x + (size_t)arow * 32 + quad * 8;
        float4 v0 = *(const float4*)xp;
        float4 v1 = *(const float4*)(xp + 4);
        a[0] = (short)f2bf(v0.x); a[1] = (short)f2bf(v0.y);
        a[2] = (short)f2bf(v0.z); a[3] = (short)f2bf(v0.w);
        a[4] = (short)f2bf(v1.x); a[5] = (short)f2bf(v1.y);
        a[6] = (short)f2bf(v1.z); a[7] = (short)f2bf(v1.w);
    }
    f32x4 acc[8];
    #pragma unroll
    for (int nt = 0; nt < 8; ++nt) {
        bf16x8 b = *(const bf16x8*)(Wf + (size_t)(nt * 64 + l) * 8);
        acc[nt] = mfma16(a, b, (f32x4){0.f, 0.f, 0.f, 0.f});
    }
    #pragma unroll
    for (int reg = 0; reg < 4; ++reg) {
        int row = row0 + w * 16 + quad * 4 + reg;
        if (row < N) {
            #pragma unroll
            for (int nt = 0; nt < 8; ++nt) {
                int col = nt * 16 + l15;
                hb[(size_t)row * H + col] = f2bf(acc[nt][reg] + bias[col]);
            }
        }
    }
}

// ---------------------------------------------------------------------------
// CSR build (both edge types per dispatch)
// ---------------------------------------------------------------------------
__global__ __launch_bounds__(256)
void hist_kernel(const int* __restrict__ dstR, const int* __restrict__ dstU,
                 int* __restrict__ degR, int* __restrict__ degU, int E, int EB) {
    int bx = blockIdx.x;
    const int* dst = (bx < EB) ? dstR : dstU;
    int* deg = (bx < EB) ? degR : degU;
    int e = ((bx < EB) ? bx : bx - EB) * 256 + threadIdx.x;
    if (e < E) atomicAdd(&deg[dst[e]], 1);
}

__global__ __launch_bounds__(256)
void scan1_kernel(const int* __restrict__ degR, const int* __restrict__ degU,
                  int* __restrict__ partR, int* __restrict__ partU, int Nr, int Nu, int NBr) {
    int bx = blockIdx.x;
    const int* deg = (bx < NBr) ? degR : degU;
    int* part = (bx < NBr) ? partR : partU;
    int lb = (bx < NBr) ? bx : bx - NBr;
    int N = (bx < NBr) ? Nr : Nu;
    __shared__ int s[256];
    int t = threadIdx.x;
    int i = lb * 256 + t;
    s[t] = (i < N) ? deg[i] : 0;
    __syncthreads();
    for (int o = 128; o > 0; o >>= 1) {
        if (t < o) s[t] += s[t + o];
        __syncthreads();
    }
    if (t == 0) part[lb] = s[0];
}

__global__ __launch_bounds__(512)
void scan2_kernel(int* __restrict__ partR, int* __restrict__ partU, int nbR, int nbU) {
    int* part = (blockIdx.x == 0) ? partR : partU;
    int nb = (blockIdx.x == 0) ? nbR : nbU;
    __shared__ int s[512];
    int t = threadIdx.x;
    int v = (t < nb) ? part[t] : 0;
    s[t] = v;
    __syncthreads();
    for (int o = 1; o < 512; o <<= 1) {
        int x = (t >= o) ? s[t - o] : 0;
        __syncthreads();
        s[t] += x;
        __syncthreads();
    }
    if (t < nb) part[t] = s[t] - v;   // exclusive
}

__global__ __launch_bounds__(256)
void scan3_kernel(const int* __restrict__ degR, const int* __restrict__ degU,
                  const int* __restrict__ partR, const int* __restrict__ partU,
                  int* __restrict__ offR, int* __restrict__ offU, int Nr, int Nu, int NBr) {
    int bx = blockIdx.x;
    const int* deg = (bx < NBr) ? degR : degU;
    const int* part = (bx < NBr) ? partR : partU;
    int* off = (bx < NBr) ? offR : offU;
    int lb = (bx < NBr) ? bx : bx - NBr;
    int N = (bx < NBr) ? Nr : Nu;
    __shared__ int s[256];
    int t = threadIdx.x;
    int i = lb * 256 + t;
    int v = (i < N) ? deg[i] : 0;
    s[t] = v;
    __syncthreads();
    for (int o = 1; o < 256; o <<= 1) {
        int x = (t >= o) ? s[t - o] : 0;
        __syncthreads();
        s[t] += x;
        __syncthreads();
    }
    if (i < N) off[i] = part[lb] + s[t] - v;
    if (i == N - 1) off[N] = part[lb] + s[t];
}

__global__ __launch_bounds__(256)
void fill_kernel(const int* __restrict__ srcR, const int* __restrict__ dstR,
                 const int* __restrict__ srcU, const int* __restrict__ dstU,
                 const int* __restrict__ offR, const int* __restrict__ offU,
                 int* __restrict__ degR, int* __restrict__ degU,
                 int* __restrict__ eidR, int* __restrict__ eidU, int E, int EB) {
    int bx = blockIdx.x;
    const int* src = (bx < EB) ? srcR : srcU;
    const int* dst = (bx < EB) ? dstR : dstU;
    const int* off = (bx < EB) ? offR : offU;
    int* deg = (bx < EB) ? degR : degU;
    int* eid = (bx < EB) ? eidR : eidU;
    int e = ((bx < EB) ? bx : bx - EB) * 256 + threadIdx.x;
    if (e < E) {
        int d = dst[e];
        int p = off[d] + atomicSub(&deg[d], 1) - 1;
        eid[p] = src[e];
    }
}

// ---------------------------------------------------------------------------
// Fused layer: gather-mean + SAGE + BN + ReLU + residual, both node types.
// Gather loop unrolled x2 for memory-level parallelism.
// ---------------------------------------------------------------------------
__global__ __launch_bounds__(256)
void layer_kernel(const unsigned short* __restrict__ hu_o, const unsigned short* __restrict__ hr_o,
                  unsigned short* __restrict__ hu_n, unsigned short* __restrict__ hr_n,
                  const int* __restrict__ off_r, const int* __restrict__ eid_r,
                  const int* __restrict__ off_u, const int* __restrict__ eid_u,
                  int Nu, int Nr, int nbr,
                  const unsigned short* __restrict__ WfR, const float* __restrict__ blR,
                  const float* __restrict__ gR, const float* __restrict__ bR,
                  const float* __restrict__ mR, const float* __restrict__ vR,
                  const unsigned short* __restrict__ WfU, const float* __restrict__ blU,
                  const float* __restrict__ gU, const float* __restrict__ bU,
                  const float* __restrict__ mU, const float* __restrict__ vU) {
    int bx = blockIdx.x;
    const unsigned short* gsrc; const unsigned short* own; unsigned short* outp;
    const int* off; const int* eid; const unsigned short* Wf;
    const float *bl, *bg, *bb, *bm, *bv;
    int N, row0;
    if (bx < nbr) {
        gsrc = hu_o; own = hr_o; outp = hr_n; off = off_r; eid = eid_r;
        Wf = WfR; bl = blR; bg = gR; bb = bR; bm = mR; bv = vR;
        N = Nr; row0 = bx * 64;
    } else {
        gsrc = hr_o; own = hu_o; outp = hu_n; off = off_u; eid = eid_u;
        Wf = WfU; bl = blU; bg = gU; bb = bU; bm = mU; bv = vU;
        N = Nu; row0 = (bx - nbr) * 64;
    }

    __shared__ float sc[128], sh[128], bias[128];
    int tid = threadIdx.x;
    if (tid < 128) {
        float s = bg[tid] * rsqrtf(bv[tid] + BN_EPS);
        sc[tid] = s;
        sh[tid] = bb[tid] - bm[tid] * s;
        bias[tid] = bl[tid];
    }
    __syncthreads();

    int l = tid & 63, w = tid >> 6, l15 = l & 15, quad = l >> 4;
    int arow = row0 + w * 16 + l15;
    bool rok = (arow < N);
    size_t rbase = (size_t)(rok ? arow : 0) * H;
    int s0 = rok ? off[arow] : 0;
    int s1 = rok ? off[arow + 1] : 0;

    // gather-mean into per-lane A-fragment slices, unrolled x2
    float ag[4][8];
    #pragma unroll
    for (int kc = 0; kc < 4; ++kc)
        #pragma unroll
        for (int j = 0; j < 8; ++j) ag[kc][j] = 0.0f;

    int i = s0;
    for (; i + 2 <= s1; i += 2) {
        int sa = eid[i], sb = eid[i + 1];
        const unsigned short* rpa = gsrc + (size_t)sa * H + quad * 8;
        const unsigned short* rpb = gsrc + (size_t)sb * H + quad * 8;
        bf16x8 va[4], vb[4];
        #pragma unroll
        for (int kc = 0; kc < 4; ++kc) va[kc] = *(const bf16x8*)(rpa + kc * 32);
        #pragma unroll
        for (int kc = 0; kc < 4; ++kc) vb[kc] = *(const bf16x8*)(rpb + kc * 32);
        #pragma unroll
        for (int kc = 0; kc < 4; ++kc)
            #pragma unroll
            for (int j = 0; j < 8; ++j)
                ag[kc][j] += bf2f((unsigned short)va[kc][j]) + bf2f((unsigned short)vb[kc][j]);
    }
    if (i < s1) {
        int sa = eid[i];
        const unsigned short* rpa = gsrc + (size_t)sa * H + quad * 8;
        #pragma unroll
        for (int kc = 0; kc < 4; ++kc) {
            bf16x8 va = *(const bf16x8*)(rpa + kc * 32);
            #pragma unroll
            for (int j = 0; j < 8; ++j) ag[kc][j] += bf2f((unsigned short)va[j]);
        }
    }
    float inv = (s1 > s0) ? 1.0f / (float)(s1 - s0) : 0.0f;

    f32x4 acc[8];
    #pragma unroll
    for (int nt = 0; nt < 8; ++nt) acc[nt] = (f32x4){0.f, 0.f, 0.f, 0.f};

    // chunks 0..3: aggregated neighbor mean
    #pragma unroll
    for (int kc = 0; kc < 4; ++kc) {
        bf16x8 a;
        #pragma unroll
        for (int j = 0; j < 8; ++j) a[j] = (short)f2bf(ag[kc][j] * inv);
        #pragma unroll
        for (int nt = 0; nt < 8; ++nt) {
            bf16x8 b = *(const bf16x8*)(Wf + (size_t)((kc * 8 + nt) * 64 + l) * 8);
            acc[nt] = mfma16(a, b, acc[nt]);
        }
    }
    // chunks 4..7: own row (root weight)
    #pragma unroll
    for (int kc = 4; kc < 8; ++kc) {
        bf16x8 a = *(const bf16x8*)(own + rbase + (kc - 4) * 32 + quad * 8);
        #pragma unroll
        for (int nt = 0; nt < 8; ++nt) {
            bf16x8 b = *(const bf16x8*)(Wf + (size_t)((kc * 8 + nt) * 64 + l) * 8);
            acc[nt] = mfma16(a, b, acc[nt]);
        }
    }

    // epilogue: bias -> BN -> ReLU -> + residual (bf16)
    #pragma unroll
    for (int reg = 0; reg < 4; ++reg) {
        int crow = row0 + w * 16 + quad * 4 + reg;
        if (crow < N) {
            #pragma unroll
            for (int nt = 0; nt < 8; ++nt) {
                int col = nt * 16 + l15;
                float g = acc[nt][reg] + bias[col];
                g = g * sc[col] + sh[col];
                float hv = bf2f(own[(size_t)crow * H + col]);
                outp[(size_t)crow * H + col] = f2bf(fmaxf(g, 0.0f) + hv);
            }
        }
    }
}

// ---------------------------------------------------------------------------
// Edge predictor via MFMA, 2 edge-tiles per wave (128 edges/block):
// B-fragments loaded once per (kc,nt), used for both tiles.
// ---------------------------------------------------------------------------
__global__ __launch_bounds__(256)
void ep_kernel(const unsigned short* __restrict__ hub, const unsigned short* __restrict__ hrb,
               const float* __restrict__ ea, const int* __restrict__ esrc,
               const int* __restrict__ edst,
               const unsigned short* __restrict__ W1f, const float* __restrict__ b1,
               const float* __restrict__ bng, const float* __restrict__ bnb,
               const float* __restrict__ bnm, const float* __restrict__ bnv,
               const unsigned short* __restrict__ W2f, const float* __restrict__ b2,
               const float* __restrict__ W3, const float* __restrict__ b3,
               float* __restrict__ out, int E) {
    __shared__ unsigned short h1s[128][136];
    __shared__ int se[128], de[128];
    __shared__ float sc1[128], sh1[128], bi1[128];

    int tid = threadIdx.x;
    int e0 = blockIdx.x * 128;
    if (tid < 128) {
        int e = e0 + tid;
        se[tid] = (e < E) ? esrc[e] : 0;
        de[tid] = (e < E) ? edst[e] : 0;
        float s = bng[tid] * rsqrtf(bnv[tid] + BN_EPS);
        sc1[tid] = s;
        sh1[tid] = bnb[tid] - bnm[tid] * s;
        bi1[tid] = b1[tid];
    }
    __syncthreads();

    int l = tid & 63, w = tid >> 6, l15 = l & 15, quad = l >> 4;
    int r0 = w * 16 + l15;          // tile-0 row in block
    int r1 = 64 + r0;               // tile-1 row
    size_t s0off = (size_t)se[r0] * H, d0off = (size_t)de[r0] * H;
    size_t s1off = (size_t)se[r1] * H, d1off = (size_t)de[r1] * H;
    int eA = e0 + r0, eB = e0 + r1;
    bool evA = (eA < E), evB = (eB < E);

    f32x4 acc0[8], acc1[8];
    #pragma unroll
    for (int nt = 0; nt < 8; ++nt) {
        acc0[nt] = (f32x4){0.f, 0.f, 0.f, 0.f};
        acc1[nt] = (f32x4){0.f, 0.f, 0.f, 0.f};
    }

    // ---- phase 1: K = 272 (9 chunks of 32, last padded) ----
    #pragma unroll
    for (int kc = 0; kc < 9; ++kc) {
        bf16x8 a0, a1;
        if (kc < 4) {
            a0 = *(const bf16x8*)(hub + s0off + kc * 32 + quad * 8);
            a1 = *(const bf16x8*)(hub + s1off + kc * 32 + quad * 8);
        } else if (kc < 8) {
            a0 = *(const bf16x8*)(hrb + d0off + (kc - 4) * 32 + quad * 8);
            a1 = *(const bf16x8*)(hrb + d1off + (kc - 4) * 32 + quad * 8);
        } else {
            a0 = (bf16x8){0, 0, 0, 0, 0, 0, 0, 0};
            a1 = (bf16x8){0, 0, 0, 0, 0, 0, 0, 0};
            if (quad < 2) {
                if (evA) {
                    const float* p = ea + (size_t)eA * 16 + quad * 8;
                    float4 v0 = *(const float4*)p;
                    float4 v1 = *(const float4*)(p + 4);
                    a0[0] = (short)f2bf(v0.x); a0[1] = (short)f2bf(v0.y);
                    a0[2] = (short)f2bf(v0.z); a0[3] = (short)f2bf(v0.w);
                    a0[4] = (short)f2bf(v1.x); a0[5] = (short)f2bf(v1.y);
                    a0[6] = (short)f2bf(v1.z); a0[7] = (short)f2bf(v1.w);
                }
                if (evB) {
                    const float* p = ea + (size_t)eB * 16 + quad * 8;
                    float4 v0 = *(const float4*)p;
                    float4 v1 = *(const float4*)(p + 4);
                    a1[0] = (short)f2bf(v0.x); a1[1] = (short)f2bf(v0.y);
                    a1[2] = (short)f2bf(v0.z); a1[3] = (short)f2bf(v0.w);
                    a1[4] = (short)f2bf(v1.x); a1[5] = (short)f2bf(v1.y);
                    a1[6] = (short)f2bf(v1.z); a1[7] = (short)f2bf(v1.w);
                }
            }
        }
        #pragma unroll
        for (int nt = 0; nt < 8; ++nt) {
            bf16x8 b = *(const bf16x8*)(W1f + (size_t)((kc * 8 + nt) * 64 + l) * 8);
            acc0[nt] = mfma16(a0, b, acc0[nt]);
            acc1[nt] = mfma16(a1, b, acc1[nt]);
        }
    }

    // phase-1 epilogue: bias -> relu -> bn -> bf16 h1s (both tiles)
    #pragma unroll
    for (int nt = 0; nt < 8; ++nt) {
        #pragma unroll
        for (int reg = 0; reg < 4; ++reg) {
            int row = w * 16 + quad * 4 + reg;
            int col = nt * 16 + l15;
            float z0 = acc0[nt][reg] + bi1[col];
            z0 = fmaxf(z0, 0.0f);
            h1s[row][col] = f2bf(z0 * sc1[col] + sh1[col]);
            float z1 = acc1[nt][reg] + bi1[col];
            z1 = fmaxf(z1, 0.0f);
            h1s[64 + row][col] = f2bf(z1 * sc1[col] + sh1[col]);
        }
    }
    __syncthreads();

    // ---- phase 2: h2 = relu(h1 @ W2 + b2), K=128, N=64, both tiles ----
    f32x4 acc2a[4], acc2b[4];
    #pragma unroll
    for (int nt = 0; nt < 4; ++nt) {
        acc2a[nt] = (f32x4){0.f, 0.f, 0.f, 0.f};
        acc2b[nt] = (f32x4){0.f, 0.f, 0.f, 0.f};
    }
    #pragma unroll
    for (int kc = 0; kc < 4; ++kc) {
        bf16x8 a2a = *(const bf16x8*)&h1s[r0][kc * 32 + quad * 8];
        bf16x8 a2b = *(const bf16x8*)&h1s[r1][kc * 32 + quad * 8];
        #pragma unroll
        for (int nt = 0; nt < 4; ++nt) {
            bf16x8 b = *(const bf16x8*)(W2f + (size_t)((kc * 4 + nt) * 64 + l) * 8);
            acc2a[nt] = mfma16(a2a, b, acc2a[nt]);
            acc2b[nt] = mfma16(a2b, b, acc2b[nt]);
        }
    }

    // ---- phase 3: out = sigmoid(h2 @ W3 + b3), quad shuffle reduction ----
    float p0[4] = {0.f, 0.f, 0.f, 0.f};
    float p1[4] = {0.f, 0.f, 0.f, 0.f};
    #pragma unroll
    for (int nt = 0; nt < 4; ++nt) {
        int col = nt * 16 + l15;
        float w3v = W3[col];
        float b2v = b2[col];
        #pragma unroll
        for (int reg = 0; reg < 4; ++reg) {
            p0[reg] += fmaxf(acc2a[nt][reg] + b2v, 0.0f) * w3v;
            p1[reg] += fmaxf(acc2b[nt][reg] + b2v, 0.0f) * w3v;
        }
    }
    #pragma unroll
    for (int m = 1; m < 16; m <<= 1) {
        #pragma unroll
        for (int reg = 0; reg < 4; ++reg) {
            p0[reg] += __shfl_xor(p0[reg], m);
            p1[reg] += __shfl_xor(p1[reg], m);
        }
    }
    if (l15 < 4) {
        int row = w * 16 + quad * 4 + l15;
        int ee = e0 + row;
        if (ee < E) out[ee] = 1.0f / (1.0f + expf(-(p0[l15] + b3[0])));
        int ee1 = e0 + 64 + row;
        if (ee1 < E) out[ee1] = 1.0f / (1.0f + expf(-(p1[l15] + b3[0])));
    }
}

// ---------------------------------------------------------------------------
extern "C" void kernel_launch(void* const* d_in, const int* in_sizes, int n_in,
                              void* d_out, int out_size, void* d_ws, size_t ws_size,
                              hipStream_t stream) {
    const float* x_u     = (const float*)d_in[0];
    const float* x_r     = (const float*)d_in[1];
    const float* eattr   = (const float*)d_in[2];
    const int*   ei_ut   = (const int*)d_in[3];
    const int*   ei_ru   = (const int*)d_in[4];
    const float* proj_uW = (const float*)d_in[5];
    const float* proj_ub = (const float*)d_in[6];
    const float* proj_rW = (const float*)d_in[7];
    const float* proj_rb = (const float*)d_in[8];
    const float* sage_Wl = (const float*)d_in[9];
    const float* sage_bl = (const float*)d_in[10];
    const float* sage_Wr = (const float*)d_in[11];
    const float* bn_g    = (const float*)d_in[12];
    const float* bn_b    = (const float*)d_in[13];
    const float* bn_m    = (const float*)d_in[14];
    const float* bn_v    = (const float*)d_in[15];
    const float* ep_W1   = (const float*)d_in[16];
    const float* ep_b1   = (const float*)d_in[17];
    const float* ep_bng  = (const float*)d_in[18];
    const float* ep_bnb  = (const float*)d_in[19];
    const float* ep_bnm  = (const float*)d_in[20];
    const float* ep_bnv  = (const float*)d_in[21];
    const float* ep_W2   = (const float*)d_in[22];
    const float* ep_b2   = (const float*)d_in[23];
    const float* ep_W3   = (const float*)d_in[24];
    const float* ep_b3   = (const float*)d_in[25];

    int Nu = in_sizes[0] / 32;
    int Nr = in_sizes[1] / 32;
    int E  = in_sizes[3] / 2;

    // ---- workspace ----
    unsigned short* us = (unsigned short*)d_ws;
    unsigned short* h0_u = us;   us += (size_t)Nu * H;
    unsigned short* h0_r = us;   us += (size_t)Nr * H;
    unsigned short* h1_u = us;   us += (size_t)Nu * H;
    unsigned short* h1_r = us;   us += (size_t)Nr * H;
    unsigned short* W1f  = us;   us += 36864;
    unsigned short* W2f  = us;   us += 8192;
    unsigned short* puf  = us;   us += 4096;
    unsigned short* prf  = us;   us += 4096;
    unsigned short* sageWf = us; us += 131072;
    int* ip    = (int*)us;
    int* off_r = ip;  ip += Nr + 1;
    int* off_u = ip;  ip += Nu + 1;
    int* deg_r = ip;  ip += Nr;      // deg_r/deg_u contiguous (one memset)
    int* deg_u = ip;  ip += Nu;
    int* eid_r = ip;  ip += E;
    int* eid_u = ip;  ip += E;
    int* part_r = ip; ip += 512;
    int* part_u = ip; ip += 512;

    const int* ut_src = ei_ut;
    const int* ut_dst = ei_ut + E;
    const int* ru_src = ei_ru;
    const int* ru_dst = ei_ru + E;

    int EB  = (E + 255) / 256;
    int NBr = (Nr + 255) / 256;
    int NBu = (Nu + 255) / 256;

    // ---- weight fragments ----
    wfrag_all<<<90, 256, 0, stream>>>(ep_W1, ep_W2, proj_uW, proj_rW,
                                      sage_Wl, sage_Wr,
                                      W1f, W2f, puf, prf, sageWf);

    // ---- CSR build ----
    hipMemsetAsync(deg_r, 0, (size_t)(Nr + Nu) * sizeof(int), stream);
    hist_kernel<<<2 * EB, 256, 0, stream>>>(ut_dst, ru_dst, deg_r, deg_u, E, EB);
    scan1_kernel<<<NBr + NBu, 256, 0, stream>>>(deg_r, deg_u, part_r, part_u, Nr, Nu, NBr);
    scan2_kernel<<<2, 512, 0, stream>>>(part_r, part_u, NBr, NBu);
    scan3_kernel<<<NBr + NBu, 256, 0, stream>>>(deg_r, deg_u, part_r, part_u,
                                                off_r, off_u, Nr, Nu, NBr);
    fill_kernel<<<2 * EB, 256, 0, stream>>>(ut_src, ut_dst, ru_src, ru_dst,
                                            off_r, off_u, deg_r, deg_u,
                                            eid_r, eid_u, E, EB);

    // ---- input projections ----
    int nbu = (Nu + 63) / 64, nbr = (Nr + 63) / 64;
    proj_kernel<<<nbu + nbr, 256, 0, stream>>>(x_u, x_r, puf, proj_ub, prf, proj_rb,
                                               h0_u, h0_r, Nu, Nr, nbu);

    // ---- 2 fused layers (ping-pong h0 -> h1 -> h0) ----
    for (int layer = 0; layer < 2; ++layer) {
        const unsigned short* iu = (layer == 0) ? h0_u : h1_u;
        const unsigned short* ir = (layer == 0) ? h0_r : h1_r;
        unsigned short* ou = (layer == 0) ? h1_u : h0_u;
        unsigned short* orr = (layer == 0) ? h1_r : h0_r;

        const unsigned short* Wf0 = sageWf + ((size_t)layer * 2 + 0) * 32768;
        const unsigned short* Wf1 = sageWf + ((size_t)layer * 2 + 1) * 32768;
        const float* bl0 = sage_bl + ((size_t)layer * 2 + 0) * H;
        const float* bl1 = sage_bl + ((size_t)layer * 2 + 1) * H;
        const float* g0 = bn_g + ((size_t)layer * 2 + 0) * H;   // user BN
        const float* b0 = bn_b + ((size_t)layer * 2 + 0) * H;
        const float* m0 = bn_m + ((size_t)layer * 2 + 0) * H;
        const float* v0 = bn_v + ((size_t)layer * 2 + 0) * H;
        const float* g1 = bn_g + ((size_t)layer * 2 + 1) * H;   // recipient BN
        const float* b1 = bn_b + ((size_t)layer * 2 + 1) * H;
        const float* m1 = bn_m + ((size_t)layer * 2 + 1) * H;
        const float* v1 = bn_v + ((size_t)layer * 2 + 1) * H;

        layer_kernel<<<nbr + nbu, 256, 0, stream>>>(
            iu, ir, ou, orr,
            off_r, eid_r, off_u, eid_u,
            Nu, Nr, nbr,
            Wf0, bl0, g1, b1, m1, v1,    // recipient side (edge type 0, BN type 1)
            Wf1, bl1, g0, b0, m0, v0);   // user side (edge type 1, BN type 0)
    }

    ep_kernel<<<(E + 127) / 128, 256, 0, stream>>>(h0_u, h0_r, eattr, ut_src, ut_dst,
                                                   W1f, ep_b1,
                                                   ep_bng, ep_bnb, ep_bnm, ep_bnv,
                                                   W2f, ep_b2, ep_W3, ep_b3,
                                                   (float*)d_out, E);
}